// Round 7
// baseline (1108.105 us; speedup 1.0000x reference)
//
#include <hip/hip_runtime.h>

#define A_CNT   5
#define NB      1024
#define DIM     512
#define NMEM    16384
#define TOPK    50
#define NSTEPS  5
#define H1N     256
#define H2N     128

#define TM      128
#define TN      128
#define MSEL    100     // screen candidates per row (slack over TOPK=50)
#define RCAP    512     // candidate buffer cap

struct TileDesc { int a; int s0; int nvalid; int pad; };

typedef __bf16 bf16x8 __attribute__((ext_vector_type(8)));
typedef short  s16x8  __attribute__((ext_vector_type(8)));
typedef float  f32x4  __attribute__((ext_vector_type(4)));

// SFINAE hedge for the bf16 MFMA builtin operand type across toolchains.
template <typename T>
__device__ __forceinline__ auto mfma_try(T a, T b, f32x4 c, int)
    -> decltype(__builtin_amdgcn_mfma_f32_16x16x32_bf16(a, b, c, 0, 0, 0)) {
    return __builtin_amdgcn_mfma_f32_16x16x32_bf16(a, b, c, 0, 0, 0);
}
template <typename T>
__device__ __forceinline__ f32x4 mfma_try(T a, T b, f32x4 c, long) {
    return __builtin_amdgcn_mfma_f32_16x16x32_bf16(
        __builtin_bit_cast(s16x8, a), __builtin_bit_cast(s16x8, b), c, 0, 0, 0);
}
__device__ __forceinline__ f32x4 mfma_bf16(uint4 a, uint4 b, f32x4 c) {
    return mfma_try(__builtin_bit_cast(bf16x8, a), __builtin_bit_cast(bf16x8, b), c, 0);
}

union BF8 { bf16x8 v; uint4 u; };

// async global->LDS, 16B per lane (dest = wave-uniform base + lane*16).
__device__ __forceinline__ void gload_lds16(const void* g, void* l) {
    __builtin_amdgcn_global_load_lds(
        (const __attribute__((address_space(1))) void*)(unsigned long long)g,
        (__attribute__((address_space(3))) void*)(unsigned)(unsigned long long)l,
        16, 0, 0);
}

// ---------------------------------------------------------------------------
// k_prep_keys: fused inv-norm (VERBATIM reduction chain) + one-time fp32->bf16
// key conversion.
__global__ __launch_bounds__(256) void k_prep_keys(const float* __restrict__ keys,
                                                   float* __restrict__ inv,
                                                   unsigned short* __restrict__ kb) {
    int row  = blockIdx.x * 4 + (threadIdx.x >> 6);
    int lane = threadIdx.x & 63;
    const float* p = keys + (size_t)row * DIM;
    float ss = 0.f;
    for (int i = lane; i < DIM; i += 64) { float v = p[i]; ss += v * v; }
    for (int o = 32; o; o >>= 1) ss += __shfl_down(ss, o);
    ss = __shfl(ss, 0);
    if (lane == 0) inv[row] = 1.0f / (sqrtf(ss) + 1e-8f);
    const float4* s4 = (const float4*)(p + lane * 8);
    float4 v0 = s4[0], v1 = s4[1];
    BF8 pk;
    pk.v[0] = (__bf16)v0.x; pk.v[1] = (__bf16)v0.y;
    pk.v[2] = (__bf16)v0.z; pk.v[3] = (__bf16)v0.w;
    pk.v[4] = (__bf16)v1.x; pk.v[5] = (__bf16)v1.y;
    pk.v[6] = (__bf16)v1.z; pk.v[7] = (__bf16)v1.w;
    *(uint4*)(kb + (size_t)row * DIM + lane * 8) = pk.u;
}

// k_qnorm (step-0 only): VERBATIM fp32 path + bf16 mirror.
__global__ __launch_bounds__(256) void k_qnorm(const float* __restrict__ x,
                                               float* __restrict__ qn,
                                               unsigned short* __restrict__ qb) {
    int row = blockIdx.x, tid = threadIdx.x;
    const float* p = x + (size_t)row * DIM;
    float ss = 0.f;
    for (int i = tid; i < DIM; i += 256) { float v = p[i]; ss += v * v; }
    for (int o = 32; o; o >>= 1) ss += __shfl_down(ss, o);
    __shared__ float w4[4];
    if ((tid & 63) == 0) w4[tid >> 6] = ss;
    __syncthreads();
    float tot = w4[0] + w4[1] + w4[2] + w4[3];
    float s = 1.0f / (sqrtf(tot) + 1e-8f);
    float* q = qn + (size_t)row * DIM;
    unsigned short* qbr = qb + (size_t)row * DIM;
    for (int i = tid; i < DIM; i += 256) {
        float v = p[i] * s;
        q[i] = v;
        __bf16 h = (__bf16)v;
        qbr[i] = __builtin_bit_cast(unsigned short, h);
    }
}

// k_group_all: all NSTEPS groupings upfront (depends only on actions).
__global__ void k_group_all(const int* __restrict__ actions,
                            int* __restrict__ sorted_b_all, int* __restrict__ sorted_a_all,
                            TileDesc* __restrict__ descs_all, int cb, int maxd, int nch) {
    int t = blockIdx.x;
    int* sorted_b = sorted_b_all + t * NB;
    int* sorted_a = sorted_a_all + t * NB;
    TileDesc* descs = descs_all + t * (nch * maxd);
    int lane = threadIdx.x;  // blockDim = 64
    for (int i = lane; i < nch * maxd; i += 64) descs[i].a = -1;
    __shared__ int gs[A_CNT + 1];
    int out_pos = 0;
    for (int a = 0; a < A_CNT; a++) {
        if (lane == 0) gs[a] = out_pos;
        for (int c = 0; c < NB; c += 64) {
            int b = c + lane;
            int act = actions[b * NSTEPS + t];
            unsigned long long m = __ballot(act == a);
            int rank = __popcll(m & ((1ULL << lane) - 1ULL));
            if (act == a) { sorted_b[out_pos + rank] = b; sorted_a[out_pos + rank] = a; }
            out_pos += __popcll(m);
        }
    }
    if (lane == 0) {
        gs[A_CNT] = NB;
        int ndc[4] = {0, 0, 0, 0};
        for (int a = 0; a < A_CNT; a++) {
            int s = gs[a], e = gs[a + 1];
            while (s < e) {
                int c = s / cb;
                int lim = min(e, (c + 1) * cb);
                int len = min(TM, lim - s);
                TileDesc d; d.a = a; d.s0 = s; d.nvalid = len; d.pad = 0;
                descs[c * maxd + ndc[c]++] = d;
                s += len;
            }
        }
    }
}

// ---------------------------------------------------------------------------
// k_screen: ROUND-5/6 VERBATIM (passing, bit-verified).
__global__ __launch_bounds__(256) void k_screen(
    const unsigned short* __restrict__ qb, const unsigned short* __restrict__ kb,
    const float* __restrict__ inv_kn, const int* __restrict__ sorted_b,
    const TileDesc* __restrict__ descs, int chunk_row0,
    unsigned short* __restrict__ simsb) {
    TileDesc d = descs[blockIdx.x];
    if (d.a < 0) return;
    int tid = threadIdx.x;
    int n0 = blockIdx.y * TN;
    __shared__ __align__(16) unsigned short Qs[TM][32];
    __shared__ __align__(16) unsigned short Ks[TN][32];
    __shared__ int rows[TM];
    if (tid < TM) rows[tid] = sorted_b[d.s0 + min(tid, d.nvalid - 1)];
    __syncthreads();

    int w = tid >> 6, lane = tid & 63;
    int g = lane >> 4, r15 = lane & 15;
    int wq = w >> 1, wn = w & 1;
    int swc = (g ^ ((r15 >> 1) & 3)) * 8;   // swizzled frag column (u16 units)

    int srow = tid >> 2, schunk = ((tid & 3) ^ ((tid >> 3) & 3)) * 8;
    const unsigned short* kbase = kb + (size_t)d.a * NMEM * DIM;
    const unsigned short* q0 = qb + (size_t)rows[srow] * DIM + schunk;
    const unsigned short* q1 = qb + (size_t)rows[64 + srow] * DIM + schunk;
    const unsigned short* k0p = kbase + (size_t)(n0 + srow) * DIM + schunk;
    const unsigned short* k1p = kbase + (size_t)(n0 + 64 + srow) * DIM + schunk;
    char* ldsQ = (char*)&Qs[0][0] + tid * 16;
    char* ldsK = (char*)&Ks[0][0] + tid * 16;

    f32x4 acc[4][4];
#pragma unroll
    for (int i = 0; i < 4; i++)
#pragma unroll
        for (int j = 0; j < 4; j++) acc[i][j] = (f32x4){0.f, 0.f, 0.f, 0.f};

    for (int k0 = 0; k0 < DIM; k0 += 32) {
        gload_lds16(q0 + k0,  ldsQ);
        gload_lds16(q1 + k0,  ldsQ + 4096);
        gload_lds16(k0p + k0, ldsK);
        gload_lds16(k1p + k0, ldsK + 4096);
        __syncthreads();
        uint4 kf[4], qf[4];
#pragma unroll
        for (int m = 0; m < 4; m++)
            kf[m] = *(const uint4*)&Ks[wn * 64 + m * 16 + r15][swc];
#pragma unroll
        for (int m = 0; m < 4; m++)
            qf[m] = *(const uint4*)&Qs[wq * 64 + m * 16 + r15][swc];
#pragma unroll
        for (int i = 0; i < 4; i++)
#pragma unroll
            for (int j = 0; j < 4; j++)
                acc[i][j] = mfma_bf16(kf[i], qf[j], acc[i][j]);
        __syncthreads();
    }

    int sbase = d.s0 - chunk_row0;
#pragma unroll
    for (int j = 0; j < 4; j++) {
        int q = wq * 64 + j * 16 + r15;
        if (q < d.nvalid) {
            unsigned short* orow = simsb + (size_t)(sbase + q) * NMEM + n0;
#pragma unroll
            for (int i = 0; i < 4; i++) {
                int nb = wn * 64 + i * 16 + g * 4;
                float4 iv = *(const float4*)(inv_kn + (size_t)d.a * NMEM + n0 + nb);
                __bf16 e0 = (__bf16)(acc[i][j][0] * iv.x);
                __bf16 e1 = (__bf16)(acc[i][j][1] * iv.y);
                __bf16 e2 = (__bf16)(acc[i][j][2] * iv.z);
                __bf16 e3 = (__bf16)(acc[i][j][3] * iv.w);
                ushort4 o;
                o.x = __builtin_bit_cast(unsigned short, e0);
                o.y = __builtin_bit_cast(unsigned short, e1);
                o.z = __builtin_bit_cast(unsigned short, e2);
                o.w = __builtin_bit_cast(unsigned short, e3);
                *(ushort4*)(orow + nb) = o;
            }
        }
    }
}

// ---------------------------------------------------------------------------
// k_topk: ROUND-5/6 VERBATIM body (passing, bit-verified).
__global__ __launch_bounds__(256) void k_topk(
    const unsigned short* __restrict__ simsb,
    const int* __restrict__ sorted_b, const int* __restrict__ sorted_a,
    int chunk_row0,
    const float* __restrict__ qn, const float* __restrict__ keys,
    const float* __restrict__ inv_kn,
    const float* __restrict__ memv, float* __restrict__ cur_next,
    float* __restrict__ qn_out, unsigned short* __restrict__ qb_out) {
    int tid = threadIdx.x;
    int s = chunk_row0 + blockIdx.x;
    int b = sorted_b[s], a = sorted_a[s];
    const unsigned short* row = simsb + (size_t)blockIdx.x * NMEM;

    __shared__ unsigned cnum;
    __shared__ int   cidx[RCAP];
    __shared__ float cval[RCAP];
    __shared__ __align__(16) float qs[DIM];
    __shared__ float selw[TOPK];
    __shared__ int   seli[TOPK];
    __shared__ int   wred[2][4];
    __shared__ float w4[4];

    uint4 rr[8];
#pragma unroll
    for (int c = 0; c < 8; c++) {
        uint4 v = ((const uint4*)row)[c * 256 + tid];
        unsigned s0 = (v.x >> 15) & 0x00010001u;
        unsigned s1 = (v.y >> 15) & 0x00010001u;
        unsigned s2 = (v.z >> 15) & 0x00010001u;
        unsigned s3 = (v.w >> 15) & 0x00010001u;
        v.x ^= 0x80008000u | (s0 * 0x7FFFu);
        v.y ^= 0x80008000u | (s1 * 0x7FFFu);
        v.z ^= 0x80008000u | (s2 * 0x7FFFu);
        v.w ^= 0x80008000u | (s3 * 0x7FFFu);
        rr[c] = v;
    }

    qs[tid]       = qn[(size_t)b * DIM + tid];
    qs[tid + 256] = qn[(size_t)b * DIM + tid + 256];
    if (tid == 0) cnum = 0;

    unsigned lo = 0, hi = 65536;
    for (int it = 0; it < 16; ++it) {
        unsigned mid = (lo + hi) >> 1;
        int cnt = 0;
#pragma unroll
        for (int c = 0; c < 8; c++) {
            unsigned w0 = rr[c].x, w1 = rr[c].y, w2 = rr[c].z, w3 = rr[c].w;
            cnt += ((w0 & 0xFFFFu) >= mid) + ((w0 >> 16) >= mid);
            cnt += ((w1 & 0xFFFFu) >= mid) + ((w1 >> 16) >= mid);
            cnt += ((w2 & 0xFFFFu) >= mid) + ((w2 >> 16) >= mid);
            cnt += ((w3 & 0xFFFFu) >= mid) + ((w3 >> 16) >= mid);
        }
        for (int o = 32; o; o >>= 1) cnt += __shfl_down(cnt, o);
        if ((tid & 63) == 0) wred[it & 1][tid >> 6] = cnt;
        __syncthreads();
        int tot = wred[it & 1][0] + wred[it & 1][1] + wred[it & 1][2] + wred[it & 1][3];
        if ((unsigned)tot >= MSEL) lo = mid; else hi = mid;
    }
    unsigned tau16 = lo;

#pragma unroll
    for (int c = 0; c < 8; c++) {
        unsigned uu[4] = {rr[c].x, rr[c].y, rr[c].z, rr[c].w};
#pragma unroll
        for (int q2 = 0; q2 < 4; q2++) {
#pragma unroll
            for (int hh = 0; hh < 2; hh++) {
                unsigned u16v = hh ? (uu[q2] >> 16) : (uu[q2] & 0xFFFFu);
                if (u16v >= tau16) {
                    unsigned p = atomicAdd(&cnum, 1u);
                    if (p < RCAP) cidx[p] = (c * 256 + tid) * 8 + q2 * 2 + hh;
                }
            }
        }
    }
    __syncthreads();
    int ncand = (int)cnum; if (ncand > RCAP) ncand = RCAP;

    const float* kbase = keys + (size_t)a * NMEM * DIM;
    const float* invp  = inv_kn + (size_t)a * NMEM;
    for (int i = tid; i < ncand; i += 256) {
        int n = cidx[i];
        const float4* kr = (const float4*)(kbase + (size_t)n * DIM);
        float acc = 0.f;
#pragma unroll 8
        for (int k4 = 0; k4 < DIM / 4; k4++) {
            float4 v = kr[k4];
            float4 qv = *(const float4*)&qs[k4 * 4];
            acc = fmaf(qv.x, v.x, acc);
            acc = fmaf(qv.y, v.y, acc);
            acc = fmaf(qv.z, v.z, acc);
            acc = fmaf(qv.w, v.w, acc);
        }
        cval[i] = acc * invp[n];
    }
    __syncthreads();

    for (int i = tid; i < ncand; i += 256) {
        float si = cval[i]; int ni = cidx[i];
        int rank = 0;
        for (int j = 0; j < ncand; j++) {
            float sj = cval[j];
            rank += (sj > si) || (sj == si && cidx[j] < ni);
        }
        if (rank < TOPK) { selw[rank] = si; seli[rank] = ni; }
    }
    __syncthreads();
    if (tid == 0) {
        float mx = selw[0];
        for (int i = 1; i < TOPK; i++) mx = fmaxf(mx, selw[i]);
        float ssum = 0.f;
        for (int i = 0; i < TOPK; i++) { float e = expf(selw[i] - mx); selw[i] = e; ssum += e; }
        float inv = 1.0f / ssum;
        for (int i = 0; i < TOPK; i++) selw[i] *= inv;
    }
    __syncthreads();

    const float* mv = memv + (size_t)a * NMEM * DIM;
    float acc0 = 0.f, acc1 = 0.f;
#pragma unroll 10
    for (int i = 0; i < TOPK; i++) {
        const float* vr = mv + (size_t)seli[i] * DIM;
        float wgt = selw[i];
        acc0 += wgt * vr[tid];
        acc1 += wgt * vr[tid + 256];
    }
    float* o = cur_next + (size_t)b * DIM;
    o[tid] = acc0;
    o[tid + 256] = acc1;

    // fused qnorm: replicate k_qnorm's exact reduction on this row's values.
    float ss = 0.f;
    { float v = acc0; ss += v * v; }
    { float v = acc1; ss += v * v; }
    for (int o2 = 32; o2; o2 >>= 1) ss += __shfl_down(ss, o2);
    if ((tid & 63) == 0) w4[tid >> 6] = ss;
    __syncthreads();
    float tot = w4[0] + w4[1] + w4[2] + w4[3];
    float sc = 1.0f / (sqrtf(tot) + 1e-8f);
    float v0 = acc0 * sc, v1 = acc1 * sc;
    qn_out[(size_t)b * DIM + tid]       = v0;
    qn_out[(size_t)b * DIM + tid + 256] = v1;
    __bf16 h0 = (__bf16)v0, h1 = (__bf16)v1;
    qb_out[(size_t)b * DIM + tid]       = __builtin_bit_cast(unsigned short, h0);
    qb_out[(size_t)b * DIM + tid + 256] = __builtin_bit_cast(unsigned short, h1);
}

// ---------------------------------------------------------------------------
// k_mlp_gemm: tiled fp32 GEMM (round-0 k_gemm skeleton: 128x128 tile, KC=32,
// 8x8 micro-tile) computing y = elu(x @ w + bias). Per-output accumulation is
// a SINGLE serial chain, k ascending, initialized from bias — the exact
// summation order of the old per-row k_mlp (a0 = b1[l]; a0 += xv*w) -> output
// bit-identical. Weight tile is re-read ~once per block instead of per wave.
__global__ __launch_bounds__(256) void k_mlp_gemm(
    const float* __restrict__ x, int ldx,
    const float* __restrict__ w,      // K x N row-major
    const float* __restrict__ bias,
    float* __restrict__ y, int N, int K) {
    int m0 = blockIdx.x * 128;
    int n0 = blockIdx.y * 128;
    int tid = threadIdx.x;
    __shared__ __align__(16) float As[32][132];
    __shared__ __align__(16) float Bs[32][132];
    int ty = tid >> 4, tx = tid & 15;
    float acc[8][8];
#pragma unroll
    for (int j = 0; j < 8; j++) {
        int cc = (j < 4) ? (tx * 4 + j) : (64 + tx * 4 + (j - 4));
        float bv = bias[n0 + cc];
#pragma unroll
        for (int i = 0; i < 8; i++) acc[i][j] = bv;
    }
    for (int k0 = 0; k0 < K; k0 += 32) {
#pragma unroll
        for (int i = 0; i < 4; i++) {       // A tile: 128 rows x 32 k
            int f4 = tid + i * 256;
            int r = f4 >> 3;
            int kq = (f4 & 7) * 4;
            float4 v = *(const float4*)(x + (size_t)(m0 + r) * ldx + k0 + kq);
            As[kq + 0][r] = v.x; As[kq + 1][r] = v.y;
            As[kq + 2][r] = v.z; As[kq + 3][r] = v.w;
        }
#pragma unroll
        for (int i = 0; i < 4; i++) {       // B tile: 32 k x 128 n (k-major W)
            int f4 = tid + i * 256;
            int kk = f4 >> 5;
            int n4 = (f4 & 31) * 4;
            float4 v = *(const float4*)(w + (size_t)(k0 + kk) * N + n0 + n4);
            Bs[kk][n4 + 0] = v.x; Bs[kk][n4 + 1] = v.y;
            Bs[kk][n4 + 2] = v.z; Bs[kk][n4 + 3] = v.w;
        }
        __syncthreads();
#pragma unroll
        for (int k = 0; k < 32; k++) {
            float4 a0 = *(const float4*)&As[k][ty * 4];
            float4 a1 = *(const float4*)&As[k][64 + ty * 4];
            float4 b0 = *(const float4*)&Bs[k][tx * 4];
            float4 b1v = *(const float4*)&Bs[k][64 + tx * 4];
            float ar[8] = {a0.x, a0.y, a0.z, a0.w, a1.x, a1.y, a1.z, a1.w};
            float br[8] = {b0.x, b0.y, b0.z, b0.w, b1v.x, b1v.y, b1v.z, b1v.w};
#pragma unroll
            for (int i = 0; i < 8; i++)
#pragma unroll
                for (int j = 0; j < 8; j++) acc[i][j] += ar[i] * br[j];
        }
        __syncthreads();
    }
#pragma unroll
    for (int i = 0; i < 8; i++) {
        int r = m0 + ((i < 4) ? (ty * 4 + i) : (64 + ty * 4 + (i - 4)));
        float* orow = y + (size_t)r * N + n0;
#pragma unroll
        for (int j = 0; j < 8; j++) {
            int cc = (j < 4) ? (tx * 4 + j) : (64 + tx * 4 + (j - 4));
            float v = acc[i][j];
            orow[cc] = (v > 0.f) ? v : expm1f(v);
        }
    }
}

// k_mlp_dot: layer-3 per-row dot on ELU'd H2 — VERBATIM reduce order of the
// old k_mlp epilogue (c0+c1, shfl_down 32..1, + b3[0]) and the k_mlp_all
// output index mapping.
__global__ __launch_bounds__(256) void k_mlp_dot(
    const float* __restrict__ h2e,
    const float* __restrict__ W3, const float* __restrict__ b3,
    float* __restrict__ out) {
    int w = threadIdx.x >> 6, lane = threadIdx.x & 63;
    int r = blockIdx.x * 4 + w;
    int oidx;
    if (r < NB) oidx = r;
    else { int rr = r - NB; int t = rr / NB, b = rr - t * NB; oidx = NB + b * NSTEPS + t; }
    float c0 = h2e[(size_t)r * H2N + lane]      * W3[lane];
    float c1 = h2e[(size_t)r * H2N + lane + 64] * W3[lane + 64];
    float ssum = c0 + c1;
    for (int o = 32; o; o >>= 1) ssum += __shfl_down(ssum, o);
    if (lane == 0) out[oidx] = ssum + b3[0];
}

// ---------------------------------------------------------------------------
extern "C" void kernel_launch(void* const* d_in, const int* in_sizes, int n_in,
                              void* d_out, int out_size, void* d_ws, size_t ws_size,
                              hipStream_t stream) {
    const float* emb  = (const float*)d_in[0];
    const float* keys = (const float*)d_in[1];
    const float* memv = (const float*)d_in[2];
    const float* W1 = (const float*)d_in[3];
    const float* b1 = (const float*)d_in[4];
    const float* W2 = (const float*)d_in[5];
    const float* b2 = (const float*)d_in[6];
    const float* W3 = (const float*)d_in[7];
    const float* b3 = (const float*)d_in[8];
    const int* actions = (const int*)d_in[9];
    float* out = (float*)d_out;

    char* ws = (char*)d_ws;
    size_t off = 0;
    auto alloc = [&](size_t bytes) -> void* {
        void* p = ws + off;
        off = (off + bytes + 255) & ~(size_t)255;
        return p;
    };
    float* inv_kn  = (float*)alloc(sizeof(float) * A_CNT * NMEM);
    float* qnA     = (float*)alloc(sizeof(float) * NB * DIM);
    float* qnB     = (float*)alloc(sizeof(float) * NB * DIM);
    unsigned short* qbA = (unsigned short*)alloc(sizeof(unsigned short) * NB * DIM);
    unsigned short* qbB = (unsigned short*)alloc(sizeof(unsigned short) * NB * DIM);
    unsigned short* kb = (unsigned short*)alloc(sizeof(unsigned short) * (size_t)A_CNT * NMEM * DIM);
    float* curAll  = (float*)alloc(sizeof(float) * (size_t)NSTEPS * NB * DIM);
    float* H1      = (float*)alloc(sizeof(float) * (size_t)6 * NB * H1N);
    float* H2      = (float*)alloc(sizeof(float) * (size_t)6 * NB * H2N);
    int* sorted_b  = (int*)alloc(sizeof(int) * NSTEPS * NB);
    int* sorted_a  = (int*)alloc(sizeof(int) * NSTEPS * NB);
    TileDesc* descs = (TileDesc*)alloc(sizeof(TileDesc) * 64 * NSTEPS);
    size_t rem = (ws_size > off) ? (ws_size - off) : 0;
    int CB = 256;
    if (rem >= sizeof(unsigned short) * (size_t)1024 * NMEM + 4096) CB = 1024;
    else if (rem >= sizeof(unsigned short) * (size_t)512 * NMEM + 4096) CB = 512;
    unsigned short* simsb = (unsigned short*)alloc(sizeof(unsigned short) * (size_t)CB * NMEM);
    int nch = NB / CB;
    int maxd = CB / TM + A_CNT;

    k_prep_keys<<<dim3(A_CNT * NMEM / 4), dim3(256), 0, stream>>>(keys, inv_kn, kb);
    k_group_all<<<dim3(NSTEPS), dim3(64), 0, stream>>>(actions, sorted_b, sorted_a, descs, CB, maxd, nch);
    k_qnorm<<<dim3(NB), dim3(256), 0, stream>>>(emb, qnA, qbA);

    float* qn_cur = qnA;  unsigned short* qb_cur = qbA;
    float* qn_nxt = qnB;  unsigned short* qb_nxt = qbB;
    for (int t = 0; t < NSTEPS; t++) {
        const int* sb = sorted_b + t * NB;
        const int* sa = sorted_a + t * NB;
        TileDesc* dsc = descs + t * (nch * maxd);
        float* nxt = curAll + (size_t)t * NB * DIM;
        for (int c = 0; c < nch; c++) {
            k_screen<<<dim3(maxd, NMEM / TN), dim3(256), 0, stream>>>(
                qb_cur, kb, inv_kn, sb, dsc + c * maxd, c * CB, simsb);
            k_topk<<<dim3(CB), dim3(256), 0, stream>>>(
                simsb, sb, sa, c * CB, qn_cur, keys, inv_kn, memv, nxt, qn_nxt, qb_nxt);
        }
        { float* tf = qn_cur; qn_cur = qn_nxt; qn_nxt = tf; }
        { unsigned short* ts = qb_cur; qb_cur = qb_nxt; qb_nxt = ts; }
    }
    // MLP as 3 tiled GEMM stages over all 6144 rows.
    k_mlp_gemm<<<dim3(NB / 128, H1N / 128), dim3(256), 0, stream>>>(
        emb, DIM, W1, b1, H1, H1N, DIM);
    k_mlp_gemm<<<dim3(NSTEPS * NB / 128, H1N / 128), dim3(256), 0, stream>>>(
        curAll, DIM, W1, b1, H1 + (size_t)NB * H1N, H1N, DIM);
    k_mlp_gemm<<<dim3(6 * NB / 128, H2N / 128), dim3(256), 0, stream>>>(
        H1, H1N, W2, b2, H2, H2N, H1N);
    k_mlp_dot<<<dim3(6 * NB / 4), dim3(256), 0, stream>>>(H2, W3, b3, out);
}

// Round 8
// 1011.473 us; speedup vs baseline: 1.0955x; 1.0955x over previous
//
#include <hip/hip_runtime.h>

#define A_CNT   5
#define NB      1024
#define DIM     512
#define NMEM    16384
#define TOPK    50
#define NSTEPS  5
#define H1N     256
#define H2N     128

#define TM      128
#define TN      128
#define MSEL    100     // screen candidates per row (slack over TOPK=50)
#define RCAP    512     // candidate buffer cap

struct TileDesc { int a; int s0; int nvalid; int pad; };

typedef __bf16 bf16x8 __attribute__((ext_vector_type(8)));
typedef short  s16x8  __attribute__((ext_vector_type(8)));
typedef float  f32x4  __attribute__((ext_vector_type(4)));

// SFINAE hedge for the bf16 MFMA builtin operand type across toolchains.
template <typename T>
__device__ __forceinline__ auto mfma_try(T a, T b, f32x4 c, int)
    -> decltype(__builtin_amdgcn_mfma_f32_16x16x32_bf16(a, b, c, 0, 0, 0)) {
    return __builtin_amdgcn_mfma_f32_16x16x32_bf16(a, b, c, 0, 0, 0);
}
template <typename T>
__device__ __forceinline__ f32x4 mfma_try(T a, T b, f32x4 c, long) {
    return __builtin_amdgcn_mfma_f32_16x16x32_bf16(
        __builtin_bit_cast(s16x8, a), __builtin_bit_cast(s16x8, b), c, 0, 0, 0);
}
__device__ __forceinline__ f32x4 mfma_bf16(uint4 a, uint4 b, f32x4 c) {
    return mfma_try(__builtin_bit_cast(bf16x8, a), __builtin_bit_cast(bf16x8, b), c, 0);
}

union BF8 { bf16x8 v; uint4 u; };

// async global->LDS, 16B per lane (dest = wave-uniform base + lane*16).
__device__ __forceinline__ void gload_lds16(const void* g, void* l) {
    __builtin_amdgcn_global_load_lds(
        (const __attribute__((address_space(1))) void*)(unsigned long long)g,
        (__attribute__((address_space(3))) void*)(unsigned)(unsigned long long)l,
        16, 0, 0);
}

// ---------------------------------------------------------------------------
// k_prep_keys: fused inv-norm (VERBATIM reduction chain) + one-time fp32->bf16
// key conversion.
__global__ __launch_bounds__(256) void k_prep_keys(const float* __restrict__ keys,
                                                   float* __restrict__ inv,
                                                   unsigned short* __restrict__ kb) {
    int row  = blockIdx.x * 4 + (threadIdx.x >> 6);
    int lane = threadIdx.x & 63;
    const float* p = keys + (size_t)row * DIM;
    float ss = 0.f;
    for (int i = lane; i < DIM; i += 64) { float v = p[i]; ss += v * v; }
    for (int o = 32; o; o >>= 1) ss += __shfl_down(ss, o);
    ss = __shfl(ss, 0);
    if (lane == 0) inv[row] = 1.0f / (sqrtf(ss) + 1e-8f);
    const float4* s4 = (const float4*)(p + lane * 8);
    float4 v0 = s4[0], v1 = s4[1];
    BF8 pk;
    pk.v[0] = (__bf16)v0.x; pk.v[1] = (__bf16)v0.y;
    pk.v[2] = (__bf16)v0.z; pk.v[3] = (__bf16)v0.w;
    pk.v[4] = (__bf16)v1.x; pk.v[5] = (__bf16)v1.y;
    pk.v[6] = (__bf16)v1.z; pk.v[7] = (__bf16)v1.w;
    *(uint4*)(kb + (size_t)row * DIM + lane * 8) = pk.u;
}

// k_qnorm (step-0 only): VERBATIM fp32 path + bf16 mirror.
__global__ __launch_bounds__(256) void k_qnorm(const float* __restrict__ x,
                                               float* __restrict__ qn,
                                               unsigned short* __restrict__ qb) {
    int row = blockIdx.x, tid = threadIdx.x;
    const float* p = x + (size_t)row * DIM;
    float ss = 0.f;
    for (int i = tid; i < DIM; i += 256) { float v = p[i]; ss += v * v; }
    for (int o = 32; o; o >>= 1) ss += __shfl_down(ss, o);
    __shared__ float w4[4];
    if ((tid & 63) == 0) w4[tid >> 6] = ss;
    __syncthreads();
    float tot = w4[0] + w4[1] + w4[2] + w4[3];
    float s = 1.0f / (sqrtf(tot) + 1e-8f);
    float* q = qn + (size_t)row * DIM;
    unsigned short* qbr = qb + (size_t)row * DIM;
    for (int i = tid; i < DIM; i += 256) {
        float v = p[i] * s;
        q[i] = v;
        __bf16 h = (__bf16)v;
        qbr[i] = __builtin_bit_cast(unsigned short, h);
    }
}

// k_group_all: all NSTEPS groupings upfront (depends only on actions).
__global__ void k_group_all(const int* __restrict__ actions,
                            int* __restrict__ sorted_b_all, int* __restrict__ sorted_a_all,
                            TileDesc* __restrict__ descs_all, int cb, int maxd, int nch) {
    int t = blockIdx.x;
    int* sorted_b = sorted_b_all + t * NB;
    int* sorted_a = sorted_a_all + t * NB;
    TileDesc* descs = descs_all + t * (nch * maxd);
    int lane = threadIdx.x;  // blockDim = 64
    for (int i = lane; i < nch * maxd; i += 64) descs[i].a = -1;
    __shared__ int gs[A_CNT + 1];
    int out_pos = 0;
    for (int a = 0; a < A_CNT; a++) {
        if (lane == 0) gs[a] = out_pos;
        for (int c = 0; c < NB; c += 64) {
            int b = c + lane;
            int act = actions[b * NSTEPS + t];
            unsigned long long m = __ballot(act == a);
            int rank = __popcll(m & ((1ULL << lane) - 1ULL));
            if (act == a) { sorted_b[out_pos + rank] = b; sorted_a[out_pos + rank] = a; }
            out_pos += __popcll(m);
        }
    }
    if (lane == 0) {
        gs[A_CNT] = NB;
        int ndc[4] = {0, 0, 0, 0};
        for (int a = 0; a < A_CNT; a++) {
            int s = gs[a], e = gs[a + 1];
            while (s < e) {
                int c = s / cb;
                int lim = min(e, (c + 1) * cb);
                int len = min(TM, lim - s);
                TileDesc d; d.a = a; d.s0 = s; d.nvalid = len; d.pad = 0;
                descs[c * maxd + ndc[c]++] = d;
                s += len;
            }
        }
    }
}

// ---------------------------------------------------------------------------
// k_screen: ROUND-5/6 VERBATIM (passing, bit-verified).
__global__ __launch_bounds__(256) void k_screen(
    const unsigned short* __restrict__ qb, const unsigned short* __restrict__ kb,
    const float* __restrict__ inv_kn, const int* __restrict__ sorted_b,
    const TileDesc* __restrict__ descs, int chunk_row0,
    unsigned short* __restrict__ simsb) {
    TileDesc d = descs[blockIdx.x];
    if (d.a < 0) return;
    int tid = threadIdx.x;
    int n0 = blockIdx.y * TN;
    __shared__ __align__(16) unsigned short Qs[TM][32];
    __shared__ __align__(16) unsigned short Ks[TN][32];
    __shared__ int rows[TM];
    if (tid < TM) rows[tid] = sorted_b[d.s0 + min(tid, d.nvalid - 1)];
    __syncthreads();

    int w = tid >> 6, lane = tid & 63;
    int g = lane >> 4, r15 = lane & 15;
    int wq = w >> 1, wn = w & 1;
    int swc = (g ^ ((r15 >> 1) & 3)) * 8;   // swizzled frag column (u16 units)

    int srow = tid >> 2, schunk = ((tid & 3) ^ ((tid >> 3) & 3)) * 8;
    const unsigned short* kbase = kb + (size_t)d.a * NMEM * DIM;
    const unsigned short* q0 = qb + (size_t)rows[srow] * DIM + schunk;
    const unsigned short* q1 = qb + (size_t)rows[64 + srow] * DIM + schunk;
    const unsigned short* k0p = kbase + (size_t)(n0 + srow) * DIM + schunk;
    const unsigned short* k1p = kbase + (size_t)(n0 + 64 + srow) * DIM + schunk;
    char* ldsQ = (char*)&Qs[0][0] + tid * 16;
    char* ldsK = (char*)&Ks[0][0] + tid * 16;

    f32x4 acc[4][4];
#pragma unroll
    for (int i = 0; i < 4; i++)
#pragma unroll
        for (int j = 0; j < 4; j++) acc[i][j] = (f32x4){0.f, 0.f, 0.f, 0.f};

    for (int k0 = 0; k0 < DIM; k0 += 32) {
        gload_lds16(q0 + k0,  ldsQ);
        gload_lds16(q1 + k0,  ldsQ + 4096);
        gload_lds16(k0p + k0, ldsK);
        gload_lds16(k1p + k0, ldsK + 4096);
        __syncthreads();
        uint4 kf[4], qf[4];
#pragma unroll
        for (int m = 0; m < 4; m++)
            kf[m] = *(const uint4*)&Ks[wn * 64 + m * 16 + r15][swc];
#pragma unroll
        for (int m = 0; m < 4; m++)
            qf[m] = *(const uint4*)&Qs[wq * 64 + m * 16 + r15][swc];
#pragma unroll
        for (int i = 0; i < 4; i++)
#pragma unroll
            for (int j = 0; j < 4; j++)
                acc[i][j] = mfma_bf16(kf[i], qf[j], acc[i][j]);
        __syncthreads();
    }

    int sbase = d.s0 - chunk_row0;
#pragma unroll
    for (int j = 0; j < 4; j++) {
        int q = wq * 64 + j * 16 + r15;
        if (q < d.nvalid) {
            unsigned short* orow = simsb + (size_t)(sbase + q) * NMEM + n0;
#pragma unroll
            for (int i = 0; i < 4; i++) {
                int nb = wn * 64 + i * 16 + g * 4;
                float4 iv = *(const float4*)(inv_kn + (size_t)d.a * NMEM + n0 + nb);
                __bf16 e0 = (__bf16)(acc[i][j][0] * iv.x);
                __bf16 e1 = (__bf16)(acc[i][j][1] * iv.y);
                __bf16 e2 = (__bf16)(acc[i][j][2] * iv.z);
                __bf16 e3 = (__bf16)(acc[i][j][3] * iv.w);
                ushort4 o;
                o.x = __builtin_bit_cast(unsigned short, e0);
                o.y = __builtin_bit_cast(unsigned short, e1);
                o.z = __builtin_bit_cast(unsigned short, e2);
                o.w = __builtin_bit_cast(unsigned short, e3);
                *(ushort4*)(orow + nb) = o;
            }
        }
    }
}

// ---------------------------------------------------------------------------
// k_topk: ROUND-5/6 VERBATIM body (passing, bit-verified).
__global__ __launch_bounds__(256) void k_topk(
    const unsigned short* __restrict__ simsb,
    const int* __restrict__ sorted_b, const int* __restrict__ sorted_a,
    int chunk_row0,
    const float* __restrict__ qn, const float* __restrict__ keys,
    const float* __restrict__ inv_kn,
    const float* __restrict__ memv, float* __restrict__ cur_next,
    float* __restrict__ qn_out, unsigned short* __restrict__ qb_out) {
    int tid = threadIdx.x;
    int s = chunk_row0 + blockIdx.x;
    int b = sorted_b[s], a = sorted_a[s];
    const unsigned short* row = simsb + (size_t)blockIdx.x * NMEM;

    __shared__ unsigned cnum;
    __shared__ int   cidx[RCAP];
    __shared__ float cval[RCAP];
    __shared__ __align__(16) float qs[DIM];
    __shared__ float selw[TOPK];
    __shared__ int   seli[TOPK];
    __shared__ int   wred[2][4];
    __shared__ float w4[4];

    uint4 rr[8];
#pragma unroll
    for (int c = 0; c < 8; c++) {
        uint4 v = ((const uint4*)row)[c * 256 + tid];
        unsigned s0 = (v.x >> 15) & 0x00010001u;
        unsigned s1 = (v.y >> 15) & 0x00010001u;
        unsigned s2 = (v.z >> 15) & 0x00010001u;
        unsigned s3 = (v.w >> 15) & 0x00010001u;
        v.x ^= 0x80008000u | (s0 * 0x7FFFu);
        v.y ^= 0x80008000u | (s1 * 0x7FFFu);
        v.z ^= 0x80008000u | (s2 * 0x7FFFu);
        v.w ^= 0x80008000u | (s3 * 0x7FFFu);
        rr[c] = v;
    }

    qs[tid]       = qn[(size_t)b * DIM + tid];
    qs[tid + 256] = qn[(size_t)b * DIM + tid + 256];
    if (tid == 0) cnum = 0;

    unsigned lo = 0, hi = 65536;
    for (int it = 0; it < 16; ++it) {
        unsigned mid = (lo + hi) >> 1;
        int cnt = 0;
#pragma unroll
        for (int c = 0; c < 8; c++) {
            unsigned w0 = rr[c].x, w1 = rr[c].y, w2 = rr[c].z, w3 = rr[c].w;
            cnt += ((w0 & 0xFFFFu) >= mid) + ((w0 >> 16) >= mid);
            cnt += ((w1 & 0xFFFFu) >= mid) + ((w1 >> 16) >= mid);
            cnt += ((w2 & 0xFFFFu) >= mid) + ((w2 >> 16) >= mid);
            cnt += ((w3 & 0xFFFFu) >= mid) + ((w3 >> 16) >= mid);
        }
        for (int o = 32; o; o >>= 1) cnt += __shfl_down(cnt, o);
        if ((tid & 63) == 0) wred[it & 1][tid >> 6] = cnt;
        __syncthreads();
        int tot = wred[it & 1][0] + wred[it & 1][1] + wred[it & 1][2] + wred[it & 1][3];
        if ((unsigned)tot >= MSEL) lo = mid; else hi = mid;
    }
    unsigned tau16 = lo;

#pragma unroll
    for (int c = 0; c < 8; c++) {
        unsigned uu[4] = {rr[c].x, rr[c].y, rr[c].z, rr[c].w};
#pragma unroll
        for (int q2 = 0; q2 < 4; q2++) {
#pragma unroll
            for (int hh = 0; hh < 2; hh++) {
                unsigned u16v = hh ? (uu[q2] >> 16) : (uu[q2] & 0xFFFFu);
                if (u16v >= tau16) {
                    unsigned p = atomicAdd(&cnum, 1u);
                    if (p < RCAP) cidx[p] = (c * 256 + tid) * 8 + q2 * 2 + hh;
                }
            }
        }
    }
    __syncthreads();
    int ncand = (int)cnum; if (ncand > RCAP) ncand = RCAP;

    const float* kbase = keys + (size_t)a * NMEM * DIM;
    const float* invp  = inv_kn + (size_t)a * NMEM;
    for (int i = tid; i < ncand; i += 256) {
        int n = cidx[i];
        const float4* kr = (const float4*)(kbase + (size_t)n * DIM);
        float acc = 0.f;
#pragma unroll 8
        for (int k4 = 0; k4 < DIM / 4; k4++) {
            float4 v = kr[k4];
            float4 qv = *(const float4*)&qs[k4 * 4];
            acc = fmaf(qv.x, v.x, acc);
            acc = fmaf(qv.y, v.y, acc);
            acc = fmaf(qv.z, v.z, acc);
            acc = fmaf(qv.w, v.w, acc);
        }
        cval[i] = acc * invp[n];
    }
    __syncthreads();

    for (int i = tid; i < ncand; i += 256) {
        float si = cval[i]; int ni = cidx[i];
        int rank = 0;
        for (int j = 0; j < ncand; j++) {
            float sj = cval[j];
            rank += (sj > si) || (sj == si && cidx[j] < ni);
        }
        if (rank < TOPK) { selw[rank] = si; seli[rank] = ni; }
    }
    __syncthreads();
    if (tid == 0) {
        float mx = selw[0];
        for (int i = 1; i < TOPK; i++) mx = fmaxf(mx, selw[i]);
        float ssum = 0.f;
        for (int i = 0; i < TOPK; i++) { float e = expf(selw[i] - mx); selw[i] = e; ssum += e; }
        float inv = 1.0f / ssum;
        for (int i = 0; i < TOPK; i++) selw[i] *= inv;
    }
    __syncthreads();

    const float* mv = memv + (size_t)a * NMEM * DIM;
    float acc0 = 0.f, acc1 = 0.f;
#pragma unroll 10
    for (int i = 0; i < TOPK; i++) {
        const float* vr = mv + (size_t)seli[i] * DIM;
        float wgt = selw[i];
        acc0 += wgt * vr[tid];
        acc1 += wgt * vr[tid + 256];
    }
    float* o = cur_next + (size_t)b * DIM;
    o[tid] = acc0;
    o[tid + 256] = acc1;

    // fused qnorm: replicate k_qnorm's exact reduction on this row's values.
    float ss = 0.f;
    { float v = acc0; ss += v * v; }
    { float v = acc1; ss += v * v; }
    for (int o2 = 32; o2; o2 >>= 1) ss += __shfl_down(ss, o2);
    if ((tid & 63) == 0) w4[tid >> 6] = ss;
    __syncthreads();
    float tot = w4[0] + w4[1] + w4[2] + w4[3];
    float sc = 1.0f / (sqrtf(tot) + 1e-8f);
    float v0 = acc0 * sc, v1 = acc1 * sc;
    qn_out[(size_t)b * DIM + tid]       = v0;
    qn_out[(size_t)b * DIM + tid + 256] = v1;
    __bf16 h0 = (__bf16)v0, h1 = (__bf16)v1;
    qb_out[(size_t)b * DIM + tid]       = __builtin_bit_cast(unsigned short, h0);
    qb_out[(size_t)b * DIM + tid + 256] = __builtin_bit_cast(unsigned short, h1);
}

// ---------------------------------------------------------------------------
// k_mlp_l12: ONE launch, 768 blocks x 8 rows. Thread owns 4 consecutive
// output cols -> all weight reads are coalesced float4 (the round-6 kernel's
// bottleneck was 4B scalar weight loads: VALUBusy 14%, L2-latency-bound).
// Per-output accumulation chain is IDENTICAL to the verified per-row k_mlp:
// acc = bias[c]; k ascending; acc += x[k]*W[k][c]; ELU = (v>0)?v:expm1f(v)
// -> bit-identical H2. Layer 3 stays in k_mlp_dot (verified bit-exact).
__global__ __launch_bounds__(256) void k_mlp_l12(
    const float* __restrict__ emb, const float* __restrict__ steps,
    const float* __restrict__ W1, const float* __restrict__ b1,
    const float* __restrict__ W2, const float* __restrict__ b2,
    float* __restrict__ h2e) {
    int tid = threadIdx.x;
    int row0 = blockIdx.x * 8;
    __shared__ __align__(16) float xs[8][DIM];
    __shared__ __align__(16) float h1s[8][H1N];

    {   // stage 8 input rows: 32 threads/row, 16 floats each
        int r = tid >> 5, cb = (tid & 31) * 16;
        int rr = row0 + r;
        const float* xr = (rr < NB) ? (emb + (size_t)rr * DIM)
                                    : (steps + (size_t)(rr - NB) * DIM);
#pragma unroll
        for (int i = 0; i < 4; i++) {
            float4 v = *(const float4*)(xr + cb + i * 4);
            *(float4*)&xs[r][cb + i * 4] = v;
        }
    }
    __syncthreads();

    {   // layer 1: cols c4..c4+3, rows rg*2, rg*2+1 per thread
        int c4 = (tid & 63) * 4, rg = tid >> 6;
        int r0 = rg * 2, r1 = rg * 2 + 1;
        float a0[4], a1[4];
#pragma unroll
        for (int j = 0; j < 4; j++) { float bv = b1[c4 + j]; a0[j] = bv; a1[j] = bv; }
        for (int k = 0; k < DIM; k++) {
            float4 wv = *(const float4*)(W1 + (size_t)k * H1N + c4);
            float x0 = xs[r0][k], x1 = xs[r1][k];
            a0[0] += x0 * wv.x; a0[1] += x0 * wv.y; a0[2] += x0 * wv.z; a0[3] += x0 * wv.w;
            a1[0] += x1 * wv.x; a1[1] += x1 * wv.y; a1[2] += x1 * wv.z; a1[3] += x1 * wv.w;
        }
#pragma unroll
        for (int j = 0; j < 4; j++) {
            float v0 = a0[j], v1 = a1[j];
            h1s[r0][c4 + j] = (v0 > 0.f) ? v0 : expm1f(v0);
            h1s[r1][c4 + j] = (v1 > 0.f) ? v1 : expm1f(v1);
        }
    }
    __syncthreads();

    {   // layer 2: cols c4..c4+3, one row per thread
        int c4 = (tid & 31) * 4, r = tid >> 5;
        float a[4];
#pragma unroll
        for (int j = 0; j < 4; j++) a[j] = b2[c4 + j];
        for (int k = 0; k < H1N; k++) {
            float4 wv = *(const float4*)(W2 + (size_t)k * H2N + c4);
            float hv = h1s[r][k];
            a[0] += hv * wv.x; a[1] += hv * wv.y; a[2] += hv * wv.z; a[3] += hv * wv.w;
        }
        float4 o;
        o.x = (a[0] > 0.f) ? a[0] : expm1f(a[0]);
        o.y = (a[1] > 0.f) ? a[1] : expm1f(a[1]);
        o.z = (a[2] > 0.f) ? a[2] : expm1f(a[2]);
        o.w = (a[3] > 0.f) ? a[3] : expm1f(a[3]);
        *(float4*)(h2e + (size_t)(row0 + r) * H2N + c4) = o;
    }
}

// k_mlp_dot: ROUND-7 VERBATIM (verified bit-exact reduce + output mapping).
__global__ __launch_bounds__(256) void k_mlp_dot(
    const float* __restrict__ h2e,
    const float* __restrict__ W3, const float* __restrict__ b3,
    float* __restrict__ out) {
    int w = threadIdx.x >> 6, lane = threadIdx.x & 63;
    int r = blockIdx.x * 4 + w;
    int oidx;
    if (r < NB) oidx = r;
    else { int rr = r - NB; int t = rr / NB, b = rr - t * NB; oidx = NB + b * NSTEPS + t; }
    float c0 = h2e[(size_t)r * H2N + lane]      * W3[lane];
    float c1 = h2e[(size_t)r * H2N + lane + 64] * W3[lane + 64];
    float ssum = c0 + c1;
    for (int o = 32; o; o >>= 1) ssum += __shfl_down(ssum, o);
    if (lane == 0) out[oidx] = ssum + b3[0];
}

// ---------------------------------------------------------------------------
extern "C" void kernel_launch(void* const* d_in, const int* in_sizes, int n_in,
                              void* d_out, int out_size, void* d_ws, size_t ws_size,
                              hipStream_t stream) {
    const float* emb  = (const float*)d_in[0];
    const float* keys = (const float*)d_in[1];
    const float* memv = (const float*)d_in[2];
    const float* W1 = (const float*)d_in[3];
    const float* b1 = (const float*)d_in[4];
    const float* W2 = (const float*)d_in[5];
    const float* b2 = (const float*)d_in[6];
    const float* W3 = (const float*)d_in[7];
    const float* b3 = (const float*)d_in[8];
    const int* actions = (const int*)d_in[9];
    float* out = (float*)d_out;

    char* ws = (char*)d_ws;
    size_t off = 0;
    auto alloc = [&](size_t bytes) -> void* {
        void* p = ws + off;
        off = (off + bytes + 255) & ~(size_t)255;
        return p;
    };
    float* inv_kn  = (float*)alloc(sizeof(float) * A_CNT * NMEM);
    float* qnA     = (float*)alloc(sizeof(float) * NB * DIM);
    float* qnB     = (float*)alloc(sizeof(float) * NB * DIM);
    unsigned short* qbA = (unsigned short*)alloc(sizeof(unsigned short) * NB * DIM);
    unsigned short* qbB = (unsigned short*)alloc(sizeof(unsigned short) * NB * DIM);
    unsigned short* kb = (unsigned short*)alloc(sizeof(unsigned short) * (size_t)A_CNT * NMEM * DIM);
    float* curAll  = (float*)alloc(sizeof(float) * (size_t)NSTEPS * NB * DIM);
    float* H2      = (float*)alloc(sizeof(float) * (size_t)6 * NB * H2N);
    int* sorted_b  = (int*)alloc(sizeof(int) * NSTEPS * NB);
    int* sorted_a  = (int*)alloc(sizeof(int) * NSTEPS * NB);
    TileDesc* descs = (TileDesc*)alloc(sizeof(TileDesc) * 64 * NSTEPS);
    size_t rem = (ws_size > off) ? (ws_size - off) : 0;
    int CB = 256;
    if (rem >= sizeof(unsigned short) * (size_t)1024 * NMEM + 4096) CB = 1024;
    else if (rem >= sizeof(unsigned short) * (size_t)512 * NMEM + 4096) CB = 512;
    unsigned short* simsb = (unsigned short*)alloc(sizeof(unsigned short) * (size_t)CB * NMEM);
    int nch = NB / CB;
    int maxd = CB / TM + A_CNT;

    k_prep_keys<<<dim3(A_CNT * NMEM / 4), dim3(256), 0, stream>>>(keys, inv_kn, kb);
    k_group_all<<<dim3(NSTEPS), dim3(64), 0, stream>>>(actions, sorted_b, sorted_a, descs, CB, maxd, nch);
    k_qnorm<<<dim3(NB), dim3(256), 0, stream>>>(emb, qnA, qbA);

    float* qn_cur = qnA;  unsigned short* qb_cur = qbA;
    float* qn_nxt = qnB;  unsigned short* qb_nxt = qbB;
    for (int t = 0; t < NSTEPS; t++) {
        const int* sb = sorted_b + t * NB;
        const int* sa = sorted_a + t * NB;
        TileDesc* dsc = descs + t * (nch * maxd);
        float* nxt = curAll + (size_t)t * NB * DIM;
        for (int c = 0; c < nch; c++) {
            k_screen<<<dim3(maxd, NMEM / TN), dim3(256), 0, stream>>>(
                qb_cur, kb, inv_kn, sb, dsc + c * maxd, c * CB, simsb);
            k_topk<<<dim3(CB), dim3(256), 0, stream>>>(
                simsb, sb, sa, c * CB, qn_cur, keys, inv_kn, memv, nxt, qn_nxt, qb_nxt);
        }
        { float* tf = qn_cur; qn_cur = qn_nxt; qn_nxt = tf; }
        { unsigned short* ts = qb_cur; qb_cur = qb_nxt; qb_nxt = ts; }
    }
    // MLP: one wide layer-1/2 launch (768 blocks) + verified dot epilogue.
    k_mlp_l12<<<dim3(6 * NB / 8), dim3(256), 0, stream>>>(
        emb, curAll, W1, b1, W2, b2, H2);
    k_mlp_dot<<<dim3(6 * NB / 4), dim3(256), 0, stream>>>(H2, W3, b3, out);
}